// Round 1
// baseline (1651.440 us; speedup 1.0000x reference)
//
#include <hip/hip_runtime.h>
#include <math.h>

#define B_    8
#define M_    512
#define DM_   1024
#define H_    16
#define DH_   64
#define DFF_  4096
#define RA_   32
#define RF_   384
#define RO_   384
#define ROWS_ 4096   // B_*M_

// ---------------------------------------------------------------------------
// Repack Pq/Pk/Pv [H,DM,RA] -> Pcat [DM, 3*H*RA] with col = proj*512 + h*32 + r
// ---------------------------------------------------------------------------
__global__ __launch_bounds__(256) void repack_kernel(
    const float* __restrict__ Pq, const float* __restrict__ Pk,
    const float* __restrict__ Pv, float* __restrict__ Pcat)
{
    int idx = blockIdx.x * 256 + threadIdx.x;      // over 3*16*1024*32 = 1572864
    int r    = idx & 31;
    int d    = (idx >> 5) & 1023;
    int h    = (idx >> 15) & 15;
    int proj = idx >> 19;
    const float* P = (proj == 0) ? Pq : (proj == 1) ? Pk : Pv;
    Pcat[d * 1536 + proj * 512 + h * 32 + r] = P[(h * 1024 + d) * 32 + r];
}

// ---------------------------------------------------------------------------
// Generic fp32 GEMM: C[M,N] = A[M,K] @ B[K,N], 64x64 tile, BK=16, 256 threads.
// EPI: 0 = none, 2 = gelu(acc + bias), 3 = acc + bias + resid
// All of M,N % 64 == 0 and K % 16 == 0 in this problem.
// ---------------------------------------------------------------------------
template <int EPI>
__global__ __launch_bounds__(256) void gemm_kernel(
    const float* __restrict__ A, const float* __restrict__ Bm,
    float* __restrict__ C, int Mdim, int Ndim, int Kdim,
    const float* __restrict__ bias, const float* __restrict__ resid)
{
    __shared__ float As[16][68];   // [k][m], padded so float4 reads stay aligned
    __shared__ float Bs[16][64];   // [k][n]

    const int row0 = blockIdx.y * 64;
    const int col0 = blockIdx.x * 64;
    const int t  = threadIdx.x;
    const int tx = t & 15;
    const int ty = t >> 4;

    // A-tile load mapping: thread t -> row ar, k-offset ac (float4)
    const int ar = t >> 2;
    const int ac = (t & 3) * 4;
    // B-tile load mapping: thread t -> k-row bkr, col offset bc (float4)
    const int bkr = t >> 4;
    const int bc  = (t & 15) * 4;

    const float* Aptr = A + (size_t)(row0 + ar) * Kdim + ac;
    const float* Bptr = Bm + (size_t)bkr * Ndim + col0 + bc;

    float acc[4][4] = {};

    for (int kk = 0; kk < Kdim; kk += 16) {
        float4 av = *(const float4*)(Aptr + kk);
        float4 bv = *(const float4*)(Bptr + (size_t)kk * Ndim);
        __syncthreads();
        As[ac + 0][ar] = av.x;
        As[ac + 1][ar] = av.y;
        As[ac + 2][ar] = av.z;
        As[ac + 3][ar] = av.w;
        *(float4*)&Bs[bkr][bc] = bv;
        __syncthreads();
#pragma unroll
        for (int k = 0; k < 16; k++) {
            float4 a4 = *(const float4*)&As[k][ty * 4];
            float4 b4 = *(const float4*)&Bs[k][tx * 4];
            float a[4] = {a4.x, a4.y, a4.z, a4.w};
            float b[4] = {b4.x, b4.y, b4.z, b4.w};
#pragma unroll
            for (int i = 0; i < 4; i++)
#pragma unroll
                for (int j = 0; j < 4; j++) acc[i][j] += a[i] * b[j];
        }
    }

#pragma unroll
    for (int i = 0; i < 4; i++) {
        int r = row0 + ty * 4 + i;
        float out[4];
#pragma unroll
        for (int j = 0; j < 4; j++) {
            int c = col0 + tx * 4 + j;
            float v = acc[i][j];
            if (EPI == 2) {
                v += bias[c];
                v = 0.5f * v * (1.0f + erff(v * 0.70710678118654752f));
            } else if (EPI == 3) {
                v += bias[c] + resid[(size_t)r * Ndim + c];
            }
            out[j] = v;
        }
        *(float4*)(C + (size_t)r * Ndim + col0 + tx * 4) =
            make_float4(out[0], out[1], out[2], out[3]);
    }
}

// ---------------------------------------------------------------------------
// QKV stage 2: Q/K/V[proj][b,h,m,dh] = xp[b*512+m, proj*512+h*32 + r] @ Vx[h][r,dh] + bias
// one thread per output element, 64 threads share one (proj,b,h,m) row.
// ---------------------------------------------------------------------------
__global__ __launch_bounds__(256) void qkv2_kernel(
    const float* __restrict__ xp,
    const float* __restrict__ Vq, const float* __restrict__ Vk,
    const float* __restrict__ Vv,
    const float* __restrict__ bq, const float* __restrict__ bk,
    const float* __restrict__ bv, float* __restrict__ out)
{
    int gid = blockIdx.x * 256 + threadIdx.x;      // 3*8*16*512*64 total
    int dh = gid & 63;
    int g  = gid >> 6;            // (proj, b, h, m)
    int m  = g & 511;
    int h  = (g >> 9) & 15;
    int b  = (g >> 13) & 7;
    int proj = g >> 16;

    const float* Vmat = ((proj == 0) ? Vq : (proj == 1) ? Vk : Vv) + h * RA_ * DH_;
    const float* bias = ((proj == 0) ? bq : (proj == 1) ? bk : bv) + h * DH_;
    const float* xr = xp + (size_t)(b * 512 + m) * 1536 + proj * 512 + h * 32;

    float acc = bias[dh];
#pragma unroll
    for (int r = 0; r < 32; r++) acc += xr[r] * Vmat[r * 64 + dh];

    out[(size_t)proj * (128 * 512 * 64) + ((size_t)(b * 16 + h) * 512 + m) * 64 + dh] = acc;
}

// ---------------------------------------------------------------------------
// Fused attention, online softmax. One thread = one query row.
// Grid = B*H*2 (each block does 256 of the 512 query rows of one (b,h)).
// Writes output heads-merged: out[b, m, h*64+dh].
// ---------------------------------------------------------------------------
__global__ __launch_bounds__(256) void attn_kernel(
    const float* __restrict__ Q, const float* __restrict__ K,
    const float* __restrict__ V, const float* __restrict__ mask,
    float* __restrict__ out)
{
    __shared__ float Kt[64 * 64];
    __shared__ float Vt[64 * 64];
    __shared__ float ms[64];

    int wg = blockIdx.x;
    int mhalf = wg & 1;
    int bh = wg >> 1;
    int h = bh & 15;
    int b = bh >> 4;
    int t = threadIdx.x;
    int m = mhalf * 256 + t;

    const float* Qrow = Q + ((size_t)bh * 512 + m) * 64;
    float q[64], O[64];
#pragma unroll
    for (int i = 0; i < 16; i++) {
        float4 v = ((const float4*)Qrow)[i];
        q[4 * i] = v.x; q[4 * i + 1] = v.y; q[4 * i + 2] = v.z; q[4 * i + 3] = v.w;
    }
#pragma unroll
    for (int d = 0; d < 64; d++) O[d] = 0.0f;
    float mrun = -3.0e38f, lrun = 0.0f;

    for (int n0 = 0; n0 < 512; n0 += 64) {
        __syncthreads();
        const float* Kp = K + ((size_t)bh * 512 + n0) * 64;
        const float* Vp = V + ((size_t)bh * 512 + n0) * 64;
#pragma unroll
        for (int j = 0; j < 4; j++) {
            int idx = j * 256 + t;            // 64*64/4 = 1024 float4s
            ((float4*)Kt)[idx] = ((const float4*)Kp)[idx];
            ((float4*)Vt)[idx] = ((const float4*)Vp)[idx];
        }
        if (t < 64) ms[t] = mask[b * 512 + n0 + t];
        __syncthreads();

        for (int n = 0; n < 64; n++) {
            const float* kr = Kt + n * 64;
            float s = 0.0f;
#pragma unroll
            for (int d = 0; d < 64; d++) s += q[d] * kr[d];
            s = s * 0.125f + ms[n];
            float nm = fmaxf(mrun, s);
            float alpha = expf(mrun - nm);
            float p = expf(s - nm);
            lrun = lrun * alpha + p;
            const float* vr = Vt + n * 64;
#pragma unroll
            for (int d = 0; d < 64; d++) O[d] = O[d] * alpha + p * vr[d];
            mrun = nm;
        }
    }

    float inv = 1.0f / lrun;
    float* op = out + ((size_t)(b * 512 + m)) * 1024 + h * 64;
#pragma unroll
    for (int i = 0; i < 16; i++) {
        ((float4*)op)[i] = make_float4(O[4 * i] * inv, O[4 * i + 1] * inv,
                                       O[4 * i + 2] * inv, O[4 * i + 3] * inv);
    }
}

// ---------------------------------------------------------------------------
// Row LayerNorm over 1024 cols; one block (256 threads) per row.
// ---------------------------------------------------------------------------
__global__ __launch_bounds__(256) void ln_kernel(
    const float* __restrict__ in, const float* __restrict__ g,
    const float* __restrict__ bta, float* __restrict__ out)
{
    int row = blockIdx.x;
    int t = threadIdx.x;
    const float* x = in + (size_t)row * 1024;
    float4 xv = ((const float4*)x)[t];
    float s  = xv.x + xv.y + xv.z + xv.w;
    float ss = xv.x * xv.x + xv.y * xv.y + xv.z * xv.z + xv.w * xv.w;
#pragma unroll
    for (int off = 32; off > 0; off >>= 1) {
        s  += __shfl_down(s, off);
        ss += __shfl_down(ss, off);
    }
    __shared__ float rs[4], rss[4];
    int wid = t >> 6, lane = t & 63;
    if (lane == 0) { rs[wid] = s; rss[wid] = ss; }
    __syncthreads();
    s  = rs[0] + rs[1] + rs[2] + rs[3];
    ss = rss[0] + rss[1] + rss[2] + rss[3];
    float mu  = s * (1.0f / 1024.0f);
    float var = ss * (1.0f / 1024.0f) - mu * mu;
    float inv = rsqrtf(var + 1e-12f);
    float4 gv = ((const float4*)g)[t];
    float4 bv = ((const float4*)bta)[t];
    ((float4*)(out + (size_t)row * 1024))[t] = make_float4(
        (xv.x - mu) * inv * gv.x + bv.x, (xv.y - mu) * inv * gv.y + bv.y,
        (xv.z - mu) * inv * gv.z + bv.z, (xv.w - mu) * inv * gv.w + bv.w);
}

// ---------------------------------------------------------------------------
extern "C" void kernel_launch(void* const* d_in, const int* in_sizes, int n_in,
                              void* d_out, int out_size, void* d_ws, size_t ws_size,
                              hipStream_t stream)
{
    const float* x       = (const float*)d_in[0];
    const float* mask    = (const float*)d_in[1];
    const float* Pq      = (const float*)d_in[2];
    const float* Vq      = (const float*)d_in[3];
    const float* Pk      = (const float*)d_in[4];
    const float* Vk      = (const float*)d_in[5];
    const float* Pv      = (const float*)d_in[6];
    const float* Vv      = (const float*)d_in[7];
    const float* bq      = (const float*)d_in[8];
    const float* bk      = (const float*)d_in[9];
    const float* bv      = (const float*)d_in[10];
    const float* Uo      = (const float*)d_in[11];
    const float* Vo      = (const float*)d_in[12];
    const float* bo_attn = (const float*)d_in[13];
    const float* U1      = (const float*)d_in[14];
    const float* V1      = (const float*)d_in[15];
    const float* b1      = (const float*)d_in[16];
    const float* U2      = (const float*)d_in[17];
    const float* V2      = (const float*)d_in[18];
    const float* b2      = (const float*)d_in[19];
    const float* ln1_g   = (const float*)d_in[20];
    const float* ln1_b   = (const float*)d_in[21];
    const float* ln2_g   = (const float*)d_in[22];
    const float* ln2_b   = (const float*)d_in[23];
    float* out = (float*)d_out;

    float* ws = (float*)d_ws;
    // workspace layout (floats), with overlay:
    float* Pcat = ws;                       // 1,572,864           [K0 -> K1]
    float* xp   = ws + 1572864;             // 6,291,456           [K1 -> K2]
    float* qkv  = ws + 7864320;             // 12,582,912          [K2 -> K3]
    float* attn = ws + 20447232;            // 4,194,304           [K3 -> K4]
    float* y1   = ws + 20447232;            // 4,194,304 (reuses attn) [K5, K9]
    float* tbuf = ws + 24641536;            // 1,572,864           [t0/t1/t2]
    float* x1   = ws + 26214400;            // 4,194,304           [K5 -> end]
    float* hdn  = ws + 1572864;             // 16,777,216 (reuses xp+qkv) [K7 -> K8]

    float* Qb = qkv;
    float* Kb = qkv + 4194304;
    float* Vb = qkv + 8388608;

    // 0) repack projection weights
    repack_kernel<<<6144, 256, 0, stream>>>(Pq, Pk, Pv, Pcat);
    // 1) xp = x @ Pcat            [4096,1536] K=1024
    gemm_kernel<0><<<dim3(1536 / 64, 4096 / 64), 256, 0, stream>>>(
        x, Pcat, xp, ROWS_, 1536, 1024, nullptr, nullptr);
    // 2) Q/K/V stage 2 (K=32 per-head) + bias
    qkv2_kernel<<<49152, 256, 0, stream>>>(xp, Vq, Vk, Vv, bq, bk, bv, qkv);
    // 3) fused attention -> heads-merged attn [4096,1024]
    attn_kernel<<<256, 256, 0, stream>>>(Qb, Kb, Vb, mask, attn);
    // 4) t0 = attn @ Uo           [4096,384] K=1024
    gemm_kernel<0><<<dim3(RO_ / 64, 4096 / 64), 256, 0, stream>>>(
        attn, Uo, tbuf, ROWS_, RO_, 1024, nullptr, nullptr);
    // 5) y1 = x + t0 @ Vo + bo    [4096,1024] K=384, then LN -> x1
    gemm_kernel<3><<<dim3(1024 / 64, 4096 / 64), 256, 0, stream>>>(
        tbuf, Vo, y1, ROWS_, 1024, RO_, bo_attn, x);
    ln_kernel<<<4096, 256, 0, stream>>>(y1, ln1_g, ln1_b, x1);
    // 6) t1 = x1 @ U1             [4096,384] K=1024
    gemm_kernel<0><<<dim3(RF_ / 64, 4096 / 64), 256, 0, stream>>>(
        x1, U1, tbuf, ROWS_, RF_, 1024, nullptr, nullptr);
    // 7) hdn = gelu(t1 @ V1 + b1) [4096,4096] K=384
    gemm_kernel<2><<<dim3(DFF_ / 64, 4096 / 64), 256, 0, stream>>>(
        tbuf, V1, hdn, ROWS_, DFF_, RF_, b1, nullptr);
    // 8) t2 = hdn @ U2            [4096,384] K=4096
    gemm_kernel<0><<<dim3(RF_ / 64, 4096 / 64), 256, 0, stream>>>(
        hdn, U2, tbuf, ROWS_, RF_, 4096, nullptr, nullptr);
    // 9) y2 = x1 + t2 @ V2 + b2   [4096,1024] K=384, then LN -> out
    gemm_kernel<3><<<dim3(1024 / 64, 4096 / 64), 256, 0, stream>>>(
        tbuf, V2, y1, ROWS_, 1024, RF_, b2, x1);
    ln_kernel<<<4096, 256, 0, stream>>>(y1, ln2_g, ln2_b, out);
}

// Round 2
// 486.627 us; speedup vs baseline: 3.3936x; 3.3936x over previous
//
#include <hip/hip_runtime.h>
#include <math.h>

typedef __attribute__((ext_vector_type(8))) short short8;      // 8 bf16 (4 VGPRs)
typedef __attribute__((ext_vector_type(4))) float floatx4;     // 4 fp32 acc

__device__ inline unsigned short f2bf(float f){
    union { float f; unsigned u; } v; v.f = f;
    unsigned r = v.u + 0x7fffu + ((v.u >> 16) & 1u);   // round-to-nearest-even
    return (unsigned short)(r >> 16);
}
__device__ inline float bf2f(unsigned short b){
    union { unsigned u; float f; } v; v.u = ((unsigned)b) << 16;
    return v.f;
}
__device__ inline unsigned short to_bf(float f){ return f2bf(f); }
__device__ inline unsigned short to_bf(unsigned short u){ return u; }

// ---------------------------------------------------------------------------
// fp32 -> bf16 cast, n divisible by 1024
// ---------------------------------------------------------------------------
__global__ __launch_bounds__(256) void cast_kernel(const float* __restrict__ s,
                                                   unsigned short* __restrict__ d){
    int i = (blockIdx.x*256 + threadIdx.x)*4;
    float4 v = *(const float4*)(s+i);
    ushort4 o; o.x=f2bf(v.x); o.y=f2bf(v.y); o.z=f2bf(v.z); o.w=f2bf(v.w);
    *(ushort4*)(d+i) = o;
}

// ---------------------------------------------------------------------------
// Pq/Pk/Pv [H,DM,RA] -> Pcat_t [N=1536, K=1024] bf16 (B^T layout for GEMM)
// n = proj*512 + h*32 + r ; Pcat_t[n][d] = P[h][d][r]
// ---------------------------------------------------------------------------
__global__ __launch_bounds__(256) void repack_kernel(
    const float* __restrict__ Pq, const float* __restrict__ Pk,
    const float* __restrict__ Pv, unsigned short* __restrict__ Pt)
{
    int idx = blockIdx.x*256 + threadIdx.x;   // n*1024 + d, 1,572,864 total
    int d = idx & 1023;
    int n = idx >> 10;
    int r = n & 31, h = (n>>5)&15, proj = n>>9;
    const float* P = (proj==0)?Pq:(proj==1)?Pk:Pv;
    Pt[idx] = f2bf(P[h*32768 + d*32 + r]);
}

// ---------------------------------------------------------------------------
// Tiled transpose + cast: src [R,C] (T = float or bf16) -> dst [C,R] bf16.
// R,C multiples of 32. Batched via blockIdx.z with element strides sz/dz.
// ---------------------------------------------------------------------------
template<typename T>
__global__ __launch_bounds__(256) void trans_kernel(
    const T* __restrict__ src, unsigned short* __restrict__ dst,
    int R, int C, long sz, long dz)
{
    __shared__ unsigned short tile[32][33];
    const T* s = src + (size_t)blockIdx.z * sz;
    unsigned short* d = dst + (size_t)blockIdx.z * dz;
    int c0 = blockIdx.x*32, r0 = blockIdx.y*32;
    int tr = threadIdx.x>>3, tc = (threadIdx.x&7)*4;
    const T* sp = s + (size_t)(r0+tr)*C + c0 + tc;
#pragma unroll
    for (int i=0;i<4;i++) tile[tr][tc+i] = to_bf(sp[i]);
    __syncthreads();
    ushort4 o; o.x = tile[tc+0][tr]; o.y = tile[tc+1][tr];
    o.z = tile[tc+2][tr]; o.w = tile[tc+3][tr];
    *(ushort4*)(d + (size_t)(c0+tr)*R + r0 + tc) = o;
}

// ---------------------------------------------------------------------------
// MFMA bf16 GEMM: C[M,N] = A[M,K] @ Bt[N,K]^T, fp32 accumulate.
// Tile 64x64, BK=32, 256 threads = 4 waves in 2x2, wave does 2x2 of 16x16x32.
// Batched via blockIdx.z: base += (z>>4)*hi + (z&15)*lo strides (elements).
// EPI: 0 = bf16 store; 1 = bf16(acc*0.125 + mask[(z>>4)*512+col]);
//      2 = bf16 gelu(acc+aux[col]); 3 = f32 acc+aux[col]+resid[row*ldc+col]
// Fragment layouts (guide-verified m89/m91): a: A[m=lane&15][k=quad*8+j];
// b: B[k=quad*8+j][n=lane&15]; d: C[row=quad*4+r][col=lane&15].
// ---------------------------------------------------------------------------
template<int EPI>
__global__ __launch_bounds__(256) void mm_kernel(
    const unsigned short* __restrict__ A, const unsigned short* __restrict__ Bt,
    void* __restrict__ C, int Kdim, int lda, int ldb, int ldc,
    long ah, long al, long bh, long bl, long ch, long cl,
    const float* __restrict__ aux, const float* __restrict__ resid)
{
    __shared__ unsigned short As[64*40];   // [m][k], stride 40 keeps 16B align
    __shared__ unsigned short Bs[64*40];   // [n][k]
    int z = blockIdx.z;
    const unsigned short* Ab = A + (size_t)(z>>4)*ah + (size_t)(z&15)*al;
    const unsigned short* Bb = Bt + (size_t)(z>>4)*bh + (size_t)(z&15)*bl;
    int row0 = blockIdx.y*64, col0 = blockIdx.x*64;
    int t = threadIdx.x;
    int ar = t>>2, ak = (t&3)*8;           // staging: row, k-offset (8 bf16=16B)
    int w = t>>6, lane = t&63, quad = lane>>4, c16 = lane&15;
    int wm = (w&1)*32, wn = (w>>1)*32;

    floatx4 zero = {0.f,0.f,0.f,0.f};
    floatx4 acc[2][2];
    acc[0][0]=zero; acc[0][1]=zero; acc[1][0]=zero; acc[1][1]=zero;

    const unsigned short* Ap = Ab + (size_t)(row0+ar)*lda + ak;
    const unsigned short* Bp = Bb + (size_t)(col0+ar)*ldb + ak;

    for (int kk=0; kk<Kdim; kk+=32){
        uint4 av = *(const uint4*)(Ap + kk);
        uint4 bv = *(const uint4*)(Bp + kk);
        __syncthreads();
        *(uint4*)(As + ar*40 + ak) = av;
        *(uint4*)(Bs + ar*40 + ak) = bv;
        __syncthreads();
        short8 a0 = *(const short8*)(As + (wm   +c16)*40 + quad*8);
        short8 a1 = *(const short8*)(As + (wm+16+c16)*40 + quad*8);
        short8 b0 = *(const short8*)(Bs + (wn   +c16)*40 + quad*8);
        short8 b1 = *(const short8*)(Bs + (wn+16+c16)*40 + quad*8);
        acc[0][0] = __builtin_amdgcn_mfma_f32_16x16x32_bf16(a0,b0,acc[0][0],0,0,0);
        acc[0][1] = __builtin_amdgcn_mfma_f32_16x16x32_bf16(a0,b1,acc[0][1],0,0,0);
        acc[1][0] = __builtin_amdgcn_mfma_f32_16x16x32_bf16(a1,b0,acc[1][0],0,0,0);
        acc[1][1] = __builtin_amdgcn_mfma_f32_16x16x32_bf16(a1,b1,acc[1][1],0,0,0);
    }

    size_t zc = (size_t)(z>>4)*ch + (size_t)(z&15)*cl;
#pragma unroll
    for (int mt=0; mt<2; mt++)
#pragma unroll
    for (int r=0; r<4; r++){
        int row = row0 + wm + mt*16 + quad*4 + r;
#pragma unroll
        for (int nt=0; nt<2; nt++){
            int col = col0 + wn + nt*16 + c16;
            float v = acc[mt][nt][r];
            size_t idx = zc + (size_t)row*ldc + col;
            if (EPI==0) {
                ((unsigned short*)C)[idx] = f2bf(v);
            } else if (EPI==1) {
                ((unsigned short*)C)[idx] = f2bf(v*0.125f + aux[(size_t)(z>>4)*512 + col]);
            } else if (EPI==2) {
                v += aux[col];
                v = 0.5f*v*(1.0f + erff(v*0.70710678118654752f));
                ((unsigned short*)C)[idx] = f2bf(v);
            } else {
                ((float*)C)[idx] = v + aux[col] + resid[(size_t)row*ldc + col];
            }
        }
    }
}

// ---------------------------------------------------------------------------
// QKV stage 2 (K=32 per head) + bias; bf16 in (xp), bf16 out.
// out[proj][(b,h)][m][dh], proj stride 4,194,304 elems.
// ---------------------------------------------------------------------------
__global__ __launch_bounds__(256) void qkv2_kernel(
    const unsigned short* __restrict__ xp,
    const float* __restrict__ Vq, const float* __restrict__ Vk,
    const float* __restrict__ Vv,
    const float* __restrict__ bq, const float* __restrict__ bk,
    const float* __restrict__ bv, unsigned short* __restrict__ out)
{
    int gid = blockIdx.x*256 + threadIdx.x;
    int dh = gid & 63;
    int g  = gid >> 6;
    int m  = g & 511, h = (g>>9)&15, b = (g>>13)&7, proj = g>>16;
    const float* Vmat = ((proj==0)?Vq:(proj==1)?Vk:Vv) + h*2048;
    const float* bias = ((proj==0)?bq:(proj==1)?bk:bv) + h*64;
    const unsigned short* xr = xp + (size_t)(b*512+m)*1536 + proj*512 + h*32;
    float acc = bias[dh];
#pragma unroll
    for (int r=0;r<32;r++) acc += bf2f(xr[r]) * Vmat[r*64+dh];
    out[(size_t)proj*4194304 + ((size_t)(b*16+h)*512 + m)*64 + dh] = f2bf(acc);
}

// ---------------------------------------------------------------------------
// In-place row softmax over 512 bf16 (mask already added). 1 wave per row.
// ---------------------------------------------------------------------------
__global__ __launch_bounds__(256) void softmax_kernel(unsigned short* __restrict__ S)
{
    int row = blockIdx.x*4 + (threadIdx.x>>6);
    int lane = threadIdx.x & 63;
    unsigned short* p = S + (size_t)row*512 + lane*8;
    uint4 raw = *(const uint4*)p;
    unsigned short* u = (unsigned short*)&raw;
    float f[8];
#pragma unroll
    for (int i=0;i<8;i++) f[i] = bf2f(u[i]);
    float mx = f[0];
#pragma unroll
    for (int i=1;i<8;i++) mx = fmaxf(mx, f[i]);
#pragma unroll
    for (int off=32; off>0; off>>=1) mx = fmaxf(mx, __shfl_xor(mx, off));
    float s = 0.f;
#pragma unroll
    for (int i=0;i<8;i++){ f[i] = expf(f[i]-mx); s += f[i]; }
#pragma unroll
    for (int off=32; off>0; off>>=1) s += __shfl_xor(s, off);
    float inv = 1.0f/s;
#pragma unroll
    for (int i=0;i<8;i++) u[i] = f2bf(f[i]*inv);
    *(uint4*)p = raw;
}

// ---------------------------------------------------------------------------
// LayerNorm over 1024 cols, fp32 in/out + optional bf16 out. 1 block/row.
// ---------------------------------------------------------------------------
template<int DUAL>
__global__ __launch_bounds__(256) void ln_kernel(
    const float* __restrict__ in, const float* __restrict__ g,
    const float* __restrict__ bta, float* __restrict__ outf,
    unsigned short* __restrict__ outb)
{
    int row = blockIdx.x;
    int t = threadIdx.x;
    const float* x = in + (size_t)row*1024;
    float4 xv = ((const float4*)x)[t];
    float s  = xv.x + xv.y + xv.z + xv.w;
    float ss = xv.x*xv.x + xv.y*xv.y + xv.z*xv.z + xv.w*xv.w;
#pragma unroll
    for (int off=32; off>0; off>>=1){ s += __shfl_down(s, off); ss += __shfl_down(ss, off); }
    __shared__ float rs[4], rss[4];
    int wid = t>>6, lane = t&63;
    if (lane==0){ rs[wid]=s; rss[wid]=ss; }
    __syncthreads();
    s  = rs[0]+rs[1]+rs[2]+rs[3];
    ss = rss[0]+rss[1]+rss[2]+rss[3];
    float mu  = s * (1.0f/1024.0f);
    float var = ss * (1.0f/1024.0f) - mu*mu;
    float inv = rsqrtf(var + 1e-12f);
    float4 gv = ((const float4*)g)[t];
    float4 bv = ((const float4*)bta)[t];
    float4 o = make_float4((xv.x-mu)*inv*gv.x+bv.x, (xv.y-mu)*inv*gv.y+bv.y,
                           (xv.z-mu)*inv*gv.z+bv.z, (xv.w-mu)*inv*gv.w+bv.w);
    ((float4*)(outf + (size_t)row*1024))[t] = o;
    if (DUAL){
        ushort4 ob; ob.x=f2bf(o.x); ob.y=f2bf(o.y); ob.z=f2bf(o.z); ob.w=f2bf(o.w);
        ((ushort4*)(outb + (size_t)row*1024))[t] = ob;
    }
}

// ---------------------------------------------------------------------------
extern "C" void kernel_launch(void* const* d_in, const int* in_sizes, int n_in,
                              void* d_out, int out_size, void* d_ws, size_t ws_size,
                              hipStream_t stream)
{
    const float* x       = (const float*)d_in[0];
    const float* mask    = (const float*)d_in[1];
    const float* Pq      = (const float*)d_in[2];
    const float* Vq      = (const float*)d_in[3];
    const float* Pk      = (const float*)d_in[4];
    const float* Vk      = (const float*)d_in[5];
    const float* Pv      = (const float*)d_in[6];
    const float* Vv      = (const float*)d_in[7];
    const float* bq      = (const float*)d_in[8];
    const float* bk      = (const float*)d_in[9];
    const float* bv      = (const float*)d_in[10];
    const float* Uo      = (const float*)d_in[11];
    const float* Vo      = (const float*)d_in[12];
    const float* bo_attn = (const float*)d_in[13];
    const float* U1      = (const float*)d_in[14];
    const float* V1      = (const float*)d_in[15];
    const float* b1      = (const float*)d_in[16];
    const float* U2      = (const float*)d_in[17];
    const float* V2      = (const float*)d_in[18];
    const float* b2      = (const float*)d_in[19];
    const float* ln1_g   = (const float*)d_in[20];
    const float* ln1_b   = (const float*)d_in[21];
    const float* ln2_g   = (const float*)d_in[22];
    const float* ln2_b   = (const float*)d_in[23];
    float* out = (float*)d_out;

    // workspace layout (byte offsets, overlaid by lifetime; peak 121,634,816 B
    // == round-1 peak, known to fit)
    char* base = (char*)d_ws;
    unsigned short* Pcat_t = (unsigned short*)(base + 0);          // [1536,1024]
    unsigned short* Uo_t   = (unsigned short*)(base + 3145728);    // [384,1024]
    unsigned short* Vo_t   = (unsigned short*)(base + 3932160);    // [1024,384]
    unsigned short* U1_t   = (unsigned short*)(base + 4718592);    // [384,1024]
    unsigned short* V1_t   = (unsigned short*)(base + 5505024);    // [4096,384]
    unsigned short* U2_t   = (unsigned short*)(base + 8650752);    // [384,4096]
    unsigned short* V2_t   = (unsigned short*)(base + 11796480);   // [1024,384]
    unsigned short* Qb     = (unsigned short*)(base + 12582912);   // 128x512x64
    unsigned short* Kb     = (unsigned short*)(base + 20971520);
    unsigned short* Vb     = (unsigned short*)(base + 29360128);
    unsigned short* x_bf   = (unsigned short*)(base + 37748736);   // dies @xp
    unsigned short* xp_bf  = (unsigned short*)(base + 46137344);   // dies @qkv2
    unsigned short* S      = (unsigned short*)(base + 37748736);   // 67MB, @scores..PV
    unsigned short* attn_bf= (unsigned short*)(base + 104857600);  // @PV..Uo
    unsigned short* Vt     = (unsigned short*)(base + 113246208);  // @vtrans..PV
    unsigned short* t_bf   = (unsigned short*)(base + 37748736);   // after S dead
    float*          ybuf   = (float*)(base + 40894464);
    float*          x1     = (float*)(base + 57671680);
    unsigned short* x1_bf  = (unsigned short*)(base + 74448896);
    unsigned short* hdn_bf = (unsigned short*)(base + 82837504);   // [4096,4096]

    // --- weight prep (bf16, B^T layout) ---
    cast_kernel<<<4096,256,0,stream>>>(x, x_bf);
    trans_kernel<float><<<dim3(12,32,1),256,0,stream>>>(Uo, Uo_t, 1024,384, 0,0);
    trans_kernel<float><<<dim3(32,12,1),256,0,stream>>>(Vo, Vo_t, 384,1024, 0,0);
    trans_kernel<float><<<dim3(12,32,1),256,0,stream>>>(U1, U1_t, 1024,384, 0,0);
    trans_kernel<float><<<dim3(128,12,1),256,0,stream>>>(V1, V1_t, 384,4096, 0,0);
    trans_kernel<float><<<dim3(12,128,1),256,0,stream>>>(U2, U2_t, 4096,384, 0,0);
    trans_kernel<float><<<dim3(32,12,1),256,0,stream>>>(V2, V2_t, 384,1024, 0,0);
    repack_kernel<<<6144,256,0,stream>>>(Pq, Pk, Pv, Pcat_t);

    // --- xp = x @ Pcat  [4096,1536] K=1024 ---
    mm_kernel<0><<<dim3(24,64,1),256,0,stream>>>(x_bf, Pcat_t, xp_bf,
        1024,1024,1024,1536, 0,0,0,0,0,0, nullptr,nullptr);
    // --- QKV stage 2 ---
    qkv2_kernel<<<49152,256,0,stream>>>(xp_bf, Vq,Vk,Vv, bq,bk,bv, Qb);
    // --- scores = QK^T/8 + mask  (batched 128, [512,512] K=64) ---
    mm_kernel<1><<<dim3(8,8,128),256,0,stream>>>(Qb, Kb, S,
        64,64,64,512, 524288,32768, 524288,32768, 4194304,262144, mask,nullptr);
    // --- V -> V^T per (b,h) ---
    trans_kernel<unsigned short><<<dim3(2,16,128),256,0,stream>>>(Vb, Vt, 512,64, 32768,32768);
    // --- softmax rows ---
    softmax_kernel<<<16384,256,0,stream>>>(S);
    // --- attn = P @ V  (batched, [512,64] K=512) -> heads-merged bf16 ---
    mm_kernel<0><<<dim3(1,8,128),256,0,stream>>>(S, Vt, attn_bf,
        512,512,512,1024, 4194304,262144, 524288,32768, 524288,64, nullptr,nullptr);
    // --- t0 = attn @ Uo  [4096,384] K=1024 ---
    mm_kernel<0><<<dim3(6,64,1),256,0,stream>>>(attn_bf, Uo_t, t_bf,
        1024,1024,1024,384, 0,0,0,0,0,0, nullptr,nullptr);
    // --- y1 = x + t0 @ Vo + bo  [4096,1024] K=384 (fp32 out) ---
    mm_kernel<3><<<dim3(16,64,1),256,0,stream>>>(t_bf, Vo_t, ybuf,
        384,384,384,1024, 0,0,0,0,0,0, bo_attn, x);
    ln_kernel<1><<<4096,256,0,stream>>>(ybuf, ln1_g, ln1_b, x1, x1_bf);
    // --- t1 = x1 @ U1  [4096,384] K=1024 ---
    mm_kernel<0><<<dim3(6,64,1),256,0,stream>>>(x1_bf, U1_t, t_bf,
        1024,1024,1024,384, 0,0,0,0,0,0, nullptr,nullptr);
    // --- hdn = gelu(t1 @ V1 + b1)  [4096,4096] K=384 ---
    mm_kernel<2><<<dim3(64,64,1),256,0,stream>>>(t_bf, V1_t, hdn_bf,
        384,384,384,4096, 0,0,0,0,0,0, b1, nullptr);
    // --- t2 = hdn @ U2  [4096,384] K=4096 ---
    mm_kernel<0><<<dim3(6,64,1),256,0,stream>>>(hdn_bf, U2_t, t_bf,
        4096,4096,4096,384, 0,0,0,0,0,0, nullptr,nullptr);
    // --- y2 = x1 + t2 @ V2 + b2  [4096,1024] K=384 (fp32 out) ---
    mm_kernel<3><<<dim3(16,64,1),256,0,stream>>>(t_bf, V2_t, ybuf,
        384,384,384,1024, 0,0,0,0,0,0, b2, x1);
    ln_kernel<0><<<4096,256,0,stream>>>(ybuf, ln2_g, ln2_b, out, nullptr);
}